// Round 7
// baseline (928.179 us; speedup 1.0000x reference)
//
#include <hip/hip_runtime.h>
#include <hip/hip_bf16.h>

// B=2, S=2048, W=32, D=1024, H=16, hd=64
// Pipeline (full path):
//   bf16-cast: Wq,Wk,Wv,Wo,q (small only)
//   K/V GEMM: gemm_big = round-0 verified skeleton (256x256 tile, BK=32,
//             4-slot LDS ring 128KiB, ONE barrier per K-tile, compiler
//             fine-grained lgkmcnt for frag-read/MFMA overlap, T2 chunk-XOR
//             swizzle, T5 setprio, T1 XCD map) + FUSED fp32->bf16 A-cast:
//             per tile: CVT(st)->slot[t+3].A (st AISS'd 1 tile earlier,
//             ~3000cyc > HBM latency), AISS st<-A(t+4), STGB B(t+3).
//             Per-wave FIFO: CVT's auto vmcnt drains through A(t+3) which
//             also drains B(t+1) (needed next tile) -> no manual vmcnt in
//             steady state; vmcnt(0) only in last 3 tail tiles (free).
//             Slot(t+3)=slot(t-1): reads retired before end-(t-1) barrier.
//   Q/O GEMM: gemm_lds (128x128)
//   attn: per (b,s') head-softmax gather-attention -> A (4096x1024 bf16)
//   out  = A@Wo^T+bo (fp32)

#define DEVI __device__ __forceinline__

typedef __attribute__((ext_vector_type(8))) short bf16x8;
typedef __attribute__((ext_vector_type(4))) float f32x4;
typedef const __attribute__((address_space(1))) void* gvp;
typedef __attribute__((address_space(3))) void* lvp;

DEVI ushort f2bf(float f) {
  uint u = __float_as_uint(f);
  u = u + 0x7fffu + ((u >> 16) & 1u);
  return (ushort)(u >> 16);
}
DEVI float bf2f(ushort u) { return __uint_as_float(((uint)u) << 16); }

// ---------------- elementwise fp32 -> bf16 cast (RNE), 8 elems/thread ----
__global__ __launch_bounds__(256) void cast_kernel(const float* __restrict__ in,
                                                   ushort* __restrict__ out,
                                                   long n) {
  long i = ((long)blockIdx.x * 256 + threadIdx.x) * 8;
  const long stride = (long)gridDim.x * 256 * 8;
  for (; i < n; i += stride) {
    float4 a = *reinterpret_cast<const float4*>(in + i);
    float4 b = *reinterpret_cast<const float4*>(in + i + 4);
    ushort o[8];
    o[0] = f2bf(a.x); o[1] = f2bf(a.y); o[2] = f2bf(a.z); o[3] = f2bf(a.w);
    o[4] = f2bf(b.x); o[5] = f2bf(b.y); o[6] = f2bf(b.z); o[7] = f2bf(b.w);
    *reinterpret_cast<int4*>(out + i) = *reinterpret_cast<const int4*>(o);
  }
}

// ---------------- fused-cast round-0-skeleton GEMM ------------------------
// C = A(fp32) @ W(bf16)^T + bias (bf16 out). Tile 256(M)x256(N), K=1024,
// BK=32, 32 K-tiles, 4-slot ring (slot = A 16KB @+0 + B 16KB @+16K).
// Row = 64B = 4 chunks of 16B; stored chunk p of row r holds source chunk
// p^((r>>1)&3); fragment read swz ((lane>>4)^((lm>>1)&3))*16.
// A path per thread: 2 chunks (rows ar0, ar0+128) = 4 float4 fp32 loads ->
// 8 v_cvt_pk_bf16_f32 -> 2 ds_write_b128 (linear dest, pre-swizzled src).
// Per K-tile t: [CVT A(t+3); AISS A(t+4); STGB B(t+3)]; frag reads slot[t];
// 32 MFMA; (tail-only vmcnt(0)); s_barrier.
__global__ __launch_bounds__(512)
__attribute__((amdgpu_waves_per_eu(2, 2)))
void gemm_big(const float* __restrict__ Ag, const ushort* __restrict__ Wg,
              const float* __restrict__ bias, ushort* __restrict__ Cg) {
  constexpr int K = 1024;
  constexpr int NT = 32;       // K-tiles of 32
  constexpr int SLOT = 32768;  // 16 KB A + 16 KB B
  __shared__ char lds[4 * SLOT];
  const int tid = threadIdx.x;
  const int lane = tid & 63;
  const int wave = tid >> 6;
  const int wm = wave >> 2;  // 0..1 (M half, 128 rows)
  const int wn = wave & 3;   // 0..3 (N quarter, 64 cols)
  const int d = blockIdx.x;
  const int bn = (d >> 3) & 3;
  const size_t bm = (size_t)(d & 7) * (gridDim.x >> 5) + (d >> 5);

  const ushort* bB = Wg + (size_t)bn * 256 * K;

  // ---- staging addresses ----
  // chunk f = tid (rows 0..127) and tid+512 (rows 128..255); row = f>>2,
  // source chunk c = (f&3) ^ ((row>>1)&3)  (same c for row and row+128).
  const int ar0 = tid >> 2;
  const int ac0 = (tid & 3) ^ ((ar0 >> 1) & 3);
  // fp32 A source: chunk = 8 bf16 = 8 fp32 = 32B
  const float* pA0 = Ag + bm * 256 * K + (size_t)ar0 * K + ac0 * 8;
  const float* pA1 = pA0 + (size_t)128 * K;
  const ushort* bS0 = bB + (size_t)ar0 * K + ac0 * 8;
  const ushort* bS1 = bB + (size_t)(ar0 + 128) * K + ac0 * 8;
  const int adst0 = tid * 16;          // A region [0, 8192)
  const int adst1 = tid * 16 + 8192;   // A region [8192, 16384)
  const int bdst0 = 16384 + tid * 16;  // B region
  const int bdst1 = 24576 + tid * 16;

  // ---- fragment-read lane-invariant offsets (round-0 verified) ----
  const int lm = lane & 15;
  const int cs = (lm >> 1) & 3;
  const int cSwz = ((lane >> 4) ^ cs) * 16;
  const int offA = lm * 64 + cSwz + wm * 8192;          // + fi*1024, fi<8
  const int offB = 16384 + lm * 64 + cSwz + wn * 4096;  // + fj*1024, fj<4
  const char* ldsc = (const char*)lds;

  f32x4 acc[8][4] = {};
  float4 st[4];

#define SB0 __builtin_amdgcn_sched_barrier(0)
#define AISS4(ktE)                                               \
  {                                                              \
    st[0] = *reinterpret_cast<const float4*>(pA0 + (ktE));       \
    st[1] = *reinterpret_cast<const float4*>(pA0 + (ktE) + 4);   \
    st[2] = *reinterpret_cast<const float4*>(pA1 + (ktE));       \
    st[3] = *reinterpret_cast<const float4*>(pA1 + (ktE) + 4);   \
  }
#define CVT4(base)                                                           \
  {                                                                          \
    uint w0, w1, w2, w3;                                                     \
    asm("v_cvt_pk_bf16_f32 %0,%1,%2" : "=v"(w0) : "v"(st[0].x), "v"(st[0].y)); \
    asm("v_cvt_pk_bf16_f32 %0,%1,%2" : "=v"(w1) : "v"(st[0].z), "v"(st[0].w)); \
    asm("v_cvt_pk_bf16_f32 %0,%1,%2" : "=v"(w2) : "v"(st[1].x), "v"(st[1].y)); \
    asm("v_cvt_pk_bf16_f32 %0,%1,%2" : "=v"(w3) : "v"(st[1].z), "v"(st[1].w)); \
    *reinterpret_cast<uint4*>(lds + (base) + adst0) = make_uint4(w0, w1, w2, w3); \
    asm("v_cvt_pk_bf16_f32 %0,%1,%2" : "=v"(w0) : "v"(st[2].x), "v"(st[2].y)); \
    asm("v_cvt_pk_bf16_f32 %0,%1,%2" : "=v"(w1) : "v"(st[2].z), "v"(st[2].w)); \
    asm("v_cvt_pk_bf16_f32 %0,%1,%2" : "=v"(w2) : "v"(st[3].x), "v"(st[3].y)); \
    asm("v_cvt_pk_bf16_f32 %0,%1,%2" : "=v"(w3) : "v"(st[3].z), "v"(st[3].w)); \
    *reinterpret_cast<uint4*>(lds + (base) + adst1) = make_uint4(w0, w1, w2, w3); \
  }
#define STGB(ktE, base)                                                        \
  {                                                                            \
    __builtin_amdgcn_global_load_lds((gvp)(bS0 + (ktE)),                       \
                                     (lvp)(lds + (base) + bdst0), 16, 0, 0);   \
    __builtin_amdgcn_global_load_lds((gvp)(bS1 + (ktE)),                       \
                                     (lvp)(lds + (base) + bdst1), 16, 0, 0);   \
  }

  // ---- prologue: slots 0..2 fully staged; st = A(3) in regs ----
  AISS4(0);  SB0; CVT4(0 * SLOT); SB0;
  AISS4(32); SB0; CVT4(1 * SLOT); SB0;
  AISS4(64); SB0; CVT4(2 * SLOT); SB0;
  STGB(0, 0 * SLOT);
  STGB(32, 1 * SLOT);
  STGB(64, 2 * SLOT);
  AISS4(96); SB0;
  asm volatile("s_waitcnt vmcnt(0)" ::: "memory");
  asm volatile("s_waitcnt lgkmcnt(0)" ::: "memory");
  __builtin_amdgcn_s_barrier();
  SB0;

  int rdOff = 0, stOff = 3 * SLOT;
  for (int t = 0; t < NT; ++t) {
    // stage block: CVT A(t+3) (st from t-1), issue A(t+4), stage B(t+3)
    if (t + 3 < NT) CVT4(stOff);
    if (t + 4 < NT) AISS4((t + 4) * 32);
    if (t + 3 < NT) STGB((t + 3) * 32, stOff);
    // fragment reads (compiler emits fine-grained lgkmcnt before MFMAs)
    const char* pA = ldsc + rdOff + offA;
    const char* pB = ldsc + rdOff + offB;
    bf16x8 a[8], b[4];
#pragma unroll
    for (int fi = 0; fi < 8; ++fi)
      a[fi] = *reinterpret_cast<const bf16x8*>(pA + fi * 1024);
#pragma unroll
    for (int fj = 0; fj < 4; ++fj)
      b[fj] = *reinterpret_cast<const bf16x8*>(pB + fj * 1024);
    __builtin_amdgcn_s_setprio(1);
#pragma unroll
    for (int fi = 0; fi < 8; ++fi)
#pragma unroll
      for (int fj = 0; fj < 4; ++fj)
        acc[fi][fj] = __builtin_amdgcn_mfma_f32_16x16x32_bf16(a[fi], b[fj],
                                                              acc[fi][fj], 0, 0, 0);
    __builtin_amdgcn_s_setprio(0);
    if (t >= NT - 3 && t < NT - 1) {
      SB0;
      asm volatile("s_waitcnt vmcnt(0)" ::: "memory");
    }
    __builtin_amdgcn_s_barrier();
    rdOff = (rdOff == 3 * SLOT) ? 0 : rdOff + SLOT;
    stOff = (stOff == 3 * SLOT) ? 0 : stOff + SLOT;
  }
#undef AISS4
#undef CVT4
#undef STGB
#undef SB0

  // ---- epilogue: C/D layout col=lane&15, row=(lane>>4)*4+r ----
#pragma unroll
  for (int fi = 0; fi < 8; ++fi) {
#pragma unroll
    for (int fj = 0; fj < 4; ++fj) {
      int n = bn * 256 + wn * 64 + fj * 16 + lm;
      float bv = bias[n];
#pragma unroll
      for (int r = 0; r < 4; ++r) {
        size_t m = bm * 256 + wm * 128 + fi * 16 + ((lane >> 4) * 4) + r;
        Cg[m * 1024 + n] = f2bf(acc[fi][fj][r] + bv);
      }
    }
  }
}

// ---------------- 128x128 gload_lds GEMM (Q/O; verified) -------------------
template <typename TOUT>
__global__ __launch_bounds__(256) void gemm_lds(const ushort* __restrict__ Ag,
                                                const ushort* __restrict__ Wg,
                                                const float* __restrict__ bias,
                                                TOUT* __restrict__ Cg) {
  constexpr int K = 1024;
  __shared__ ushort lA[128 * 64];
  __shared__ ushort lB[128 * 64];
  const int tid = threadIdx.x;
  const int lane = tid & 63;
  const int wave = tid >> 6;
  const int wr = (wave >> 1) * 64;
  const int wc = (wave & 1) * 64;
  const int d = blockIdx.x;
  const int bn = (d >> 3) & 7;
  const size_t bm = (size_t)(d & 7) * (gridDim.x >> 6) + (d >> 6);

  const ushort* aB = Ag + bm * 128 * K;
  const ushort* bB = Wg + (size_t)bn * 128 * K;
  const int srow = wave * 32 + (lane >> 3);
  const int scol = ((lane & 7) ^ (lane >> 3)) * 8;
  char* lAc = (char*)lA;
  char* lBc = (char*)lB;

  f32x4 acc[4][4] = {};

  for (int kt = 0; kt < K; kt += 64) {
    __syncthreads();
#pragma unroll
    for (int c = 0; c < 4; ++c) {
      __builtin_amdgcn_global_load_lds(
          (gvp)(aB + (size_t)(srow + c * 8) * K + kt + scol),
          (lvp)(lAc + wave * 4096 + c * 1024), 16, 0, 0);
      __builtin_amdgcn_global_load_lds(
          (gvp)(bB + (size_t)(srow + c * 8) * K + kt + scol),
          (lvp)(lBc + wave * 4096 + c * 1024), 16, 0, 0);
    }
    __syncthreads();
#pragma unroll
    for (int kk = 0; kk < 2; ++kk) {
      bf16x8 af[4], bg[4];
#pragma unroll
      for (int fi = 0; fi < 4; ++fi) {
        int r = wr + fi * 16 + (lane & 15);
        int byte = (r * 128 + kk * 64 + ((lane >> 4) * 16)) ^ ((r & 7) << 4);
        af[fi] = *reinterpret_cast<const bf16x8*>(lAc + byte);
      }
#pragma unroll
      for (int fj = 0; fj < 4; ++fj) {
        int r = wc + fj * 16 + (lane & 15);
        int byte = (r * 128 + kk * 64 + ((lane >> 4) * 16)) ^ ((r & 7) << 4);
        bg[fj] = *reinterpret_cast<const bf16x8*>(lBc + byte);
      }
#pragma unroll
      for (int fi = 0; fi < 4; ++fi)
#pragma unroll
        for (int fj = 0; fj < 4; ++fj)
          acc[fi][fj] = __builtin_amdgcn_mfma_f32_16x16x32_bf16(af[fi], bg[fj],
                                                                acc[fi][fj], 0, 0, 0);
    }
  }
#pragma unroll
  for (int fi = 0; fi < 4; ++fi) {
#pragma unroll
    for (int fj = 0; fj < 4; ++fj) {
      int n = bn * 128 + wc + fj * 16 + (lane & 15);
      float bv = bias[n];
#pragma unroll
      for (int r = 0; r < 4; ++r) {
        size_t m = bm * 128 + wr + fi * 16 + ((lane >> 4) * 4) + r;
        float val = acc[fi][fj][r] + bv;
        if constexpr (sizeof(TOUT) == 2)
          reinterpret_cast<ushort*>(Cg)[m * 1024 + n] = f2bf(val);
        else
          reinterpret_cast<float*>(Cg)[m * 1024 + n] = val;
      }
    }
  }
}

// ------------- reg-staged GEMM (fp32 A): fallback path only ---------------
template <typename TIN, typename TOUT>
__global__ __launch_bounds__(256) void gemm_bias(const TIN* __restrict__ Ag,
                                                 const float* __restrict__ Wg,
                                                 const float* __restrict__ bias,
                                                 TOUT* __restrict__ Cg) {
  constexpr int K = 1024;
  __shared__ char lA[128 * 64 * 2];
  __shared__ char lB[128 * 64 * 2];
  const int tid = threadIdx.x;
  const int lane = tid & 63;
  const int wave = tid >> 6;
  const int wr = (wave >> 1) * 64;
  const int wc = (wave & 1) * 64;
  const int bn = blockIdx.x;
  const size_t bm = blockIdx.y;

  const TIN* aBase = Ag + bm * 128 * K;
  const float* bBase = Wg + (size_t)bn * 128 * K;

  f32x4 acc[4][4] = {};

  for (int kt = 0; kt < K; kt += 64) {
    __syncthreads();
    if constexpr (sizeof(TIN) == 4) {
#pragma unroll
      for (int i = 0; i < 8; ++i) {
        int f = tid + i * 256;
        int row = f >> 4, c4 = f & 15;
        const float4 v = *reinterpret_cast<const float4*>(
            reinterpret_cast<const float*>(aBase) + (size_t)row * K + kt + c4 * 4);
        ushort4 pk;
        pk.x = f2bf(v.x); pk.y = f2bf(v.y); pk.z = f2bf(v.z); pk.w = f2bf(v.w);
        int byte = (row * 128 + c4 * 8) ^ ((row & 7) << 4);
        *reinterpret_cast<ushort4*>(lA + byte) = pk;
      }
    } else {
#pragma unroll
      for (int i = 0; i < 4; ++i) {
        int f = tid + i * 256;
        int row = f >> 3, c8 = f & 7;
        int4 v = *reinterpret_cast<const int4*>(
            reinterpret_cast<const ushort*>(aBase) + (size_t)row * K + kt + c8 * 8);
        int byte = (row * 128 + c8 * 16) ^ ((row & 7) << 4);
        *reinterpret_cast<int4*>(lA + byte) = v;
      }
    }
#pragma unroll
    for (int i = 0; i < 8; ++i) {
      int f = tid + i * 256;
      int row = f >> 4, c4 = f & 15;
      const float4 v =
          *reinterpret_cast<const float4*>(bBase + (size_t)row * K + kt + c4 * 4);
      ushort4 pk;
      pk.x = f2bf(v.x); pk.y = f2bf(v.y); pk.z = f2bf(v.z); pk.w = f2bf(v.w);
      int byte = (row * 128 + c4 * 8) ^ ((row & 7) << 4);
      *reinterpret_cast<ushort4*>(lB + byte) = pk;
    }
    __syncthreads();
#pragma unroll
    for (int kk = 0; kk < 2; ++kk) {
      bf16x8 af[4], bg[4];
#pragma unroll
      for (int fi = 0; fi < 4; ++fi) {
        int r = wr + fi * 16 + (lane & 15);
        int byte = (r * 128 + kk * 64 + ((lane >> 4) * 16)) ^ ((r & 7) << 4);
        af[fi] = *reinterpret_cast<const bf16x8*>(lA + byte);
      }
#pragma unroll
      for (int fj = 0; fj < 4; ++fj) {
        int r = wc + fj * 16 + (lane & 15);
        int byte = (r * 128 + kk * 64 + ((lane >> 4) * 16)) ^ ((r & 7) << 4);
        bg[fj] = *reinterpret_cast<const bf16x8*>(lB + byte);
      }
#pragma unroll
      for (int fi = 0; fi < 4; ++fi)
#pragma unroll
        for (int fj = 0; fj < 4; ++fj)
          acc[fi][fj] =
              __builtin_amdgcn_mfma_f32_16x16x32_bf16(af[fi], bg[fj], acc[fi][fj], 0, 0, 0);
    }
  }
#pragma unroll
  for (int fi = 0; fi < 4; ++fi) {
#pragma unroll
    for (int fj = 0; fj < 4; ++fj) {
      int n = bn * 128 + wc + fj * 16 + (lane & 15);
      float bv = bias[n];
#pragma unroll
      for (int r = 0; r < 4; ++r) {
        size_t m = bm * 128 + wr + fi * 16 + ((lane >> 4) * 4) + r;
        float val = acc[fi][fj][r] + bv;
        if constexpr (sizeof(TOUT) == 2)
          reinterpret_cast<ushort*>(Cg)[m * 1024 + n] = f2bf(val);
        else
          reinterpret_cast<float*>(Cg)[m * 1024 + n] = val;
      }
    }
  }
}

// ---------------- attention: one block per (b,s'), head-axis softmax ------
__global__ __launch_bounds__(512) void attn_kernel(const ushort* __restrict__ Q,
                                                   const ushort* __restrict__ Kl,
                                                   const ushort* __restrict__ Vl,
                                                   ushort* __restrict__ Aout) {
  const int bs = blockIdx.x;
  const int b = bs >> 11, sp = bs & 2047;
  const int tid = threadIdx.x;
  const int wave = tid >> 6, lane = tid & 63;

  __shared__ ushort qrow[1024];
  __shared__ float sc[16][32];
  __shared__ float attnw[16][32];
  __shared__ float mx[32], rinv[32];

  reinterpret_cast<uint*>(qrow)[tid] =
      reinterpret_cast<const uint*>(Q + (size_t)bs * 1024)[tid];
  __syncthreads();

  const int wp = lane & 31, half = lane >> 5;
#pragma unroll
  for (int hh = 0; hh < 2; ++hh) {
    const int h = wave * 2 + hh;
    const int s_k = h * 128 + (sp >> 4);
    const int w_k = (sp & 15) * 2 + (wp >> 4);
    const ushort* kp =
        Kl + (((size_t)(b * 2048 + s_k) * 32) + w_k) * 1024 + (wp & 15) * 64 + half * 32;
    const ushort* qp = qrow + h * 64 + half * 32;
    float dot = 0.f;
#pragma unroll
    for (int j = 0; j < 32; j += 8) {
      int4 kv = *reinterpret_cast<const int4*>(kp + j);
      int4 qv = *reinterpret_cast<const int4*>(qp + j);
      const ushort* ka = reinterpret_cast<const ushort*>(&kv);
      const ushort* qa = reinterpret_cast<const ushort*>(&qv);
#pragma unroll
      for (int t = 0; t < 8; ++t) dot += bf2f(ka[t]) * bf2f(qa[t]);
    }
    dot += __shfl_xor(dot, 32);
    if (half == 0) sc[h][wp] = dot * 0.125f;
  }
  __syncthreads();
  if (tid < 32) {
    float m = sc[0][tid];
#pragma unroll
    for (int h = 1; h < 16; ++h) m = fmaxf(m, sc[h][tid]);
    float s = 0.f;
#pragma unroll
    for (int h = 0; h < 16; ++h) s += __expf(sc[h][tid] - m);
    mx[tid] = m;
    rinv[tid] = 1.f / s;
  }
  __syncthreads();
  if (lane < 32) {
#pragma unroll
    for (int hh = 0; hh < 2; ++hh) {
      const int h = wave * 2 + hh;
      attnw[h][lane] = __expf(sc[h][lane] - mx[lane]) * rinv[lane];
    }
  }
  __syncthreads();
#pragma unroll
  for (int hh = 0; hh < 2; ++hh) {
    const int h = wave * 2 + hh;
    const int s_k = h * 128 + (sp >> 4);
    const size_t vb = (((size_t)(b * 2048 + s_k) * 32) + (sp & 15) * 2) * 1024;
    float a = 0.f;
#pragma unroll
    for (int w2 = 0; w2 < 32; ++w2) {
      float wgt = attnw[h][w2];
      a += wgt * bf2f(Vl[vb + (size_t)(w2 >> 4) * 1024 + (w2 & 15) * 64 + lane]);
    }
    Aout[(((size_t)(b * 16 + h)) * 2048 + sp) * 64 + lane] = f2bf(a);
  }
}

extern "C" void kernel_launch(void* const* d_in, const int* in_sizes, int n_in,
                              void* d_out, int out_size, void* d_ws, size_t ws_size,
                              hipStream_t stream) {
  const float* q = (const float*)d_in[0];
  const float* k = (const float*)d_in[1];
  const float* v = (const float*)d_in[2];
  const float* Wq = (const float*)d_in[3];
  const float* bq = (const float*)d_in[4];
  const float* Wk = (const float*)d_in[5];
  const float* bk = (const float*)d_in[6];
  const float* Wv = (const float*)d_in[7];
  const float* bv = (const float*)d_in[8];
  const float* Wo = (const float*)d_in[9];
  const float* bo = (const float*)d_in[10];
  float* out = (float*)d_out;

  char* ws = (char*)d_ws;
  const size_t MB = 1u << 20;
  ushort* Qlin = (ushort*)ws;                    // 8 MiB
  ushort* Aws  = (ushort*)(ws + 8 * MB);         // 8 MiB
  ushort* wkbf = (ushort*)(ws + 16 * MB);        // 2 MiB
  ushort* wvbf = (ushort*)(ws + 18 * MB);        // 2 MiB
  ushort* wqbf = (ushort*)(ws + 20 * MB);        // 2 MiB
  ushort* wobf = (ushort*)(ws + 22 * MB);        // 2 MiB
  ushort* qbf  = (ushort*)(ws + 24 * MB);        // 8 MiB
  ushort* Klin = (ushort*)(ws + 32 * MB);        // 256 MiB
  ushort* Vlin = (ushort*)(ws + 288 * MB);       // 256 MiB
  const bool full = ws_size >= 800 * MB;

  if (full) {
    cast_kernel<<<dim3(512), 256, 0, stream>>>(Wq, wqbf, 1048576L);
    cast_kernel<<<dim3(512), 256, 0, stream>>>(Wk, wkbf, 1048576L);
    cast_kernel<<<dim3(512), 256, 0, stream>>>(Wv, wvbf, 1048576L);
    cast_kernel<<<dim3(512), 256, 0, stream>>>(Wo, wobf, 1048576L);
    cast_kernel<<<dim3(2048), 256, 0, stream>>>(q, qbf, 4194304L);
    gemm_lds<ushort><<<dim3(256), 256, 0, stream>>>(qbf, wqbf, bq, Qlin);
    gemm_big<<<dim3(2048), 512, 0, stream>>>(k, wkbf, bk, Klin);
    gemm_big<<<dim3(2048), 512, 0, stream>>>(v, wvbf, bv, Vlin);
    attn_kernel<<<dim3(4096), dim3(512), 0, stream>>>(Qlin, Klin, Vlin, Aws);
    gemm_lds<float><<<dim3(256), 256, 0, stream>>>(Aws, wobf, bo, out);
  } else {
    gemm_bias<float, ushort><<<dim3(8, 32), 256, 0, stream>>>(q, Wq, bq, Qlin);
    gemm_bias<float, ushort><<<dim3(8, 1024), 256, 0, stream>>>(k, Wk, bk, Klin);
    gemm_bias<float, ushort><<<dim3(8, 1024), 256, 0, stream>>>(v, Wv, bv, Vlin);
    attn_kernel<<<dim3(4096), dim3(512), 0, stream>>>(Qlin, Klin, Vlin, Aws);
    gemm_bias<ushort, float><<<dim3(8, 32), 256, 0, stream>>>(Aws, Wo, bo, out);
  }
}